// Round 1
// baseline (670.749 us; speedup 1.0000x reference)
//
#include <hip/hip_runtime.h>
#include <hip/hip_bf16.h>

#define N_NODES  50000
#define N_GRAPHS 128
#define N_EDGES  800000
#define HID      128
#define SCAN_BS  256
#define SCAN_NB  ((N_NODES + SCAN_BS - 1) / SCAN_BS)

typedef __attribute__((ext_vector_type(8))) short short8;
typedef __attribute__((ext_vector_type(4))) float f32x4;

static __device__ __forceinline__ ushort f2bf(float f){
  __hip_bfloat16 h = __float2bfloat16(f);
  return *reinterpret_cast<ushort*>(&h);
}
static __device__ __forceinline__ float bf_lo(uint pk){ return __uint_as_float(pk << 16); }
static __device__ __forceinline__ float bf_hi(uint pk){ return __uint_as_float(pk & 0xffff0000u); }

// ---------------- graph preprocessing ----------------

__global__ void k_count(const int* __restrict__ dst, int* __restrict__ deg, int E){
  int i = blockIdx.x*blockDim.x + threadIdx.x;
  if (i < E) atomicAdd(&deg[dst[i]], 1);
}

__global__ void k_scan1(const int* __restrict__ deg, int* __restrict__ lexc,
                        int* __restrict__ bsum, float* __restrict__ dinv, int N){
  __shared__ int s[SCAN_BS];
  int t = threadIdx.x, i = blockIdx.x*SCAN_BS + t;
  int v = (i < N) ? deg[i] : 0;
  if (i < N) dinv[i] = rsqrtf((float)(v + 1));   // +1 self loop
  s[t] = v;
  __syncthreads();
  int acc = v;
  for (int d = 1; d < SCAN_BS; d <<= 1){
    int u = (t >= d) ? s[t-d] : 0;
    __syncthreads();
    acc += u; s[t] = acc;
    __syncthreads();
  }
  if (i < N) lexc[i] = acc - v;
  if (t == SCAN_BS-1) bsum[blockIdx.x] = acc;
}

__global__ void k_scan2(const int* __restrict__ bsum, int* __restrict__ boff,
                        int* __restrict__ row_start){
  __shared__ int s[SCAN_NB];
  int t = threadIdx.x;
  int v = (t < SCAN_NB) ? bsum[t] : 0;
  if (t < SCAN_NB) s[t] = v;
  __syncthreads();
  int acc = v;
  for (int d = 1; d < SCAN_NB; d <<= 1){
    int u = (t >= d && t - d < SCAN_NB) ? s[t-d] : 0;
    __syncthreads();
    if (t < SCAN_NB){ acc += u; s[t] = acc; }
    __syncthreads();
  }
  if (t < SCAN_NB) boff[t] = acc - v;
  if (t == SCAN_NB-1) row_start[N_NODES] = acc;
}

__global__ void k_scan3(const int* __restrict__ lexc, const int* __restrict__ boff,
                        int* __restrict__ row_start, int N){
  int i = blockIdx.x*blockDim.x + threadIdx.x;
  if (i < N) row_start[i] = lexc[i] + boff[i >> 8];
}

__global__ void k_scatter(const int* __restrict__ src, const int* __restrict__ dst,
                          const int* __restrict__ row_start, int* __restrict__ cursor,
                          int* __restrict__ csr_src, int E){
  int i = blockIdx.x*blockDim.x + threadIdx.x;
  if (i >= E) return;
  int d = dst[i];
  int pos = row_start[d] + atomicAdd(&cursor[d], 1);
  csr_src[pos] = src[i];
}

// transpose + bf16-convert the three weight matrices in one launch
__global__ void k_wt3(const float* __restrict__ W0, ushort* __restrict__ T0,
                      const float* __restrict__ W1, ushort* __restrict__ T1,
                      const float* __restrict__ W2, ushort* __restrict__ T2){
  int idx = blockIdx.x*blockDim.x + threadIdx.x;
  if (idx < 768*HID){
    int k = idx >> 7, n = idx & 127;
    T0[n*768 + k] = f2bf(W0[idx]);
  } else if (idx < 768*HID + HID*HID){
    int j = idx - 768*HID; int k = j >> 7, n = j & 127;
    T1[n*HID + k] = f2bf(W1[j]);
  } else if (idx < 768*HID + 2*HID*HID){
    int j = idx - 768*HID - HID*HID; int k = j >> 7, n = j & 127;
    T2[n*HID + k] = f2bf(W2[j]);
  }
}

// ---------------- bf16 MFMA GEMM: Out[M][128] = A[M][K] @ W[K][128] ----------------
// CHUNKED (with OUT_BF16): write output column-chunked for the L2-pinned gather:
//   ushort index = (n>>5) * (M*32) + row*32 + (n&31)   (4 chunks of 32 cols = 64 B/row)

template<int K, bool A_F32, bool OUT_BF16, bool BIAS, bool SCALE, bool CHUNKED>
__global__ __launch_bounds__(256) void k_gemm(const void* __restrict__ Aptr,
                                              const ushort* __restrict__ Wt,
                                              const float* __restrict__ bias,
                                              const float* __restrict__ rowscale,
                                              void* __restrict__ Outp, int M){
  __shared__ __align__(16) ushort lA[64*32];    // [row][k]
  __shared__ __align__(16) ushort lB[128*32];   // [n][k]
  int tid  = threadIdx.x;
  int wave = tid >> 6, lane = tid & 63;
  int kg   = lane >> 4, lr = lane & 15;
  int m0   = blockIdx.x * 64;

  f32x4 acc[8];
  #pragma unroll
  for (int i = 0; i < 8; i++) acc[i] = f32x4{0.f, 0.f, 0.f, 0.f};

  for (int k0 = 0; k0 < K; k0 += 32){
    if (A_F32){
      const float* A = (const float*)Aptr;
      #pragma unroll
      for (int i = 0; i < 2; i++){
        int l = tid + i*256;
        int r = l >> 3, c4 = (l & 7) * 4;
        int gm = m0 + r;
        float4 v = make_float4(0.f, 0.f, 0.f, 0.f);
        if (gm < M) v = *(const float4*)(A + (size_t)gm*K + k0 + c4);
        ushort4 u; u.x = f2bf(v.x); u.y = f2bf(v.y); u.z = f2bf(v.z); u.w = f2bf(v.w);
        *(ushort4*)&lA[r*32 + c4] = u;
      }
    } else {
      const ushort* A = (const ushort*)Aptr;
      int r = tid >> 2, c8 = (tid & 3) * 8;
      int gm = m0 + r;
      int4 v = make_int4(0, 0, 0, 0);
      if (gm < M) v = *(const int4*)(A + (size_t)gm*K + k0 + c8);
      *(int4*)&lA[r*32 + c8] = v;
    }
    #pragma unroll
    for (int i = 0; i < 2; i++){
      int l = tid + i*256;
      int n = l >> 2, c8 = (l & 3) * 8;
      *(int4*)&lB[n*32 + c8] = *(const int4*)(Wt + (size_t)n*K + k0 + c8);
    }
    __syncthreads();

    short8 a = *(const short8*)&lA[(wave*16 + lr)*32 + kg*8];
    #pragma unroll
    for (int nt = 0; nt < 8; nt++){
      short8 b = *(const short8*)&lB[(nt*16 + lr)*32 + kg*8];
      acc[nt] = __builtin_amdgcn_mfma_f32_16x16x32_bf16(a, b, acc[nt], 0, 0, 0);
    }
    __syncthreads();
  }

  #pragma unroll
  for (int nt = 0; nt < 8; nt++){
    #pragma unroll
    for (int r = 0; r < 4; r++){
      int gm = m0 + wave*16 + kg*4 + r;
      int n  = nt*16 + lr;
      if (gm < M){
        float v = acc[nt][r];
        if (BIAS)  v += bias[n];
        if (SCALE) v *= rowscale[gm];
        if (OUT_BF16){
          if (CHUNKED)
            ((ushort*)Outp)[(size_t)(n >> 5)*((size_t)M*32) + (size_t)gm*32 + (n & 31)] = f2bf(v);
          else
            ((ushort*)Outp)[(size_t)gm*HID + n] = f2bf(v);
        } else {
          ((float*)Outp)[(size_t)gm*HID + n] = v;
        }
      }
    }
  }
}

// ---------------- edge aggregation (L2-pinned column chunks) ----------------
// hw is column-chunked: hwc[chunk][node][16 uints] (chunk = 32 cols = 64 B/row,
// 3.2 MB per chunk -> fits one XCD's 4 MB L2).
// chunk = blockIdx.x & 3; blocks round-robin XCDs by blockIdx % 8, so each XCD
// touches exactly ONE chunk for the whole kernel -> ~16 refs/line/XCD, gathers
// become L2 hits instead of fabric traffic.
// Wave = one (node, chunk): lanes split p = lane&15 (uint in chunk),
// q = lane>>4 (edge subgroup) -> each gather load covers 4 edges' chunks.
// Final xor-reduce over the 4 q-groups, q==0 lanes write/atomically pool.
// hw rows pre-scaled by dinv[src]; out[d] = dinv[d]*(sum + self) + bias.

template<bool RELU, bool FUSE_POOL>
__global__ __launch_bounds__(256, 4) void k_agg(const uint* __restrict__ hwc,
                                                const int* __restrict__ row_start,
                                                const int* __restrict__ csr_src,
                                                const float* __restrict__ dinv,
                                                const float* __restrict__ bias,
                                                uint* __restrict__ OutBf,
                                                const int* __restrict__ batch,
                                                const int* __restrict__ gstart,
                                                float* __restrict__ g){
  int wave = threadIdx.x >> 6, lane = threadIdx.x & 63;
  int chunk = blockIdx.x & 3;
  int node  = (blockIdx.x >> 2)*4 + wave;     // grid = 50000 blocks exactly
  int p = lane & 15, q = lane >> 4;
  const uint* __restrict__ hc = hwc + (size_t)chunk * ((size_t)N_NODES*16);

  uint pk0 = hc[(size_t)node*16 + p];         // self loop (pre-scaled)
  int b0 = row_start[node], e0 = row_start[node+1];
  float ax = (q == 0) ? bf_lo(pk0) : 0.f;
  float ay = (q == 0) ? bf_hi(pk0) : 0.f;

  for (int j0 = b0; j0 < e0; j0 += 64){
    int jj = j0 + lane;
    int sl = (jj < e0) ? __builtin_nontemporal_load(csr_src + jj) : 0; // row 0 safe for masked
    int m = e0 - j0; if (m > 64) m = 64;
    for (int i = 0; i < m; i += 16){          // 16 edges per batch = 4 gathers in flight
      uint v[4];
      #pragma unroll
      for (int u = 0; u < 4; u++){
        int s = __shfl(sl, i + 4*u + q);      // group q handles edges i+4u+q
        v[u] = hc[(size_t)s*16 + p];
      }
      #pragma unroll
      for (int u = 0; u < 4; u++){
        float mk = (i + 4*u + q < m) ? 1.0f : 0.0f;
        ax += mk * bf_lo(v[u]);
        ay += mk * bf_hi(v[u]);
      }
    }
  }

  // reduce the 4 q-groups (lanes p, p+16, p+32, p+48)
  ax += __shfl_xor(ax, 16); ax += __shfl_xor(ax, 32);
  ay += __shfl_xor(ay, 16); ay += __shfl_xor(ay, 32);

  float dd = dinv[node];
  int col = chunk*32 + 2*p;
  float vx = ax*dd + bias[col];
  float vy = ay*dd + bias[col+1];
  if (RELU){ vx = fmaxf(vx, 0.f); vy = fmaxf(vy, 0.f); }

  if (q == 0){
    if (FUSE_POOL){
      int bg = batch[node];
      float cnt = (float)(gstart[bg+1] - gstart[bg]);
      float sc = 1.0f / fmaxf(cnt, 1.0f);
      atomicAdd(&g[bg*HID + col],     vx*sc);
      atomicAdd(&g[bg*HID + col + 1], vy*sc);
    } else {
      uint pk = (uint)f2bf(vx) | ((uint)f2bf(vy) << 16);
      OutBf[(size_t)node*64 + chunk*16 + p] = pk;   // standard row layout for next GEMM
    }
  }
}

// ---------------- head ----------------

__global__ void k_ranges(const int* __restrict__ batch, int* __restrict__ gstart, int N, int G){
  int b = blockIdx.x*blockDim.x + threadIdx.x;
  if (b > G) return;
  int lo = 0, hi = N;
  while (lo < hi){ int mid = (lo + hi) >> 1; if (batch[mid] < b) lo = mid + 1; else hi = mid; }
  gstart[b] = lo;
}

__global__ void k_head(const float* __restrict__ g, const float* __restrict__ W1,
                       const float* __restrict__ b1, const float* __restrict__ W2,
                       const float* __restrict__ b2, float* __restrict__ out){
  __shared__ float row[128];
  __shared__ float z[128];
  int b = blockIdx.x, t = threadIdx.x;
  row[t] = g[b*HID + t];
  __syncthreads();
  float a = b1[t];
  #pragma unroll 8
  for (int k = 0; k < 128; k++) a += row[k] * W1[k*128 + t];
  z[t] = fmaxf(a, 0.f);
  __syncthreads();
  if (t < 3){
    float o = b2[t];
    #pragma unroll 8
    for (int k = 0; k < 128; k++) o += z[k] * W2[k*3 + t];
    out[b*3 + t] = o;
  }
}

// ---------------- launch ----------------

extern "C" void kernel_launch(void* const* d_in, const int* in_sizes, int n_in,
                              void* d_out, int out_size, void* d_ws, size_t ws_size,
                              hipStream_t stream) {
  const float* x     = (const float*)d_in[0];
  const int*   ei    = (const int*)  d_in[1];
  const int*   batch = (const int*)  d_in[2];
  const float* W_emb = (const float*)d_in[3];
  const float* b_emb = (const float*)d_in[4];
  const float* W_c1  = (const float*)d_in[5];
  const float* b_c1  = (const float*)d_in[6];
  const float* W_c2  = (const float*)d_in[7];
  const float* b_c2  = (const float*)d_in[8];
  const float* W_l1  = (const float*)d_in[9];
  const float* b_l1  = (const float*)d_in[10];
  const float* W_l2  = (const float*)d_in[11];
  const float* b_l2  = (const float*)d_in[12];
  const int* src = ei;
  const int* dst = ei + N_EDGES;
  float* out = (float*)d_out;

  char* ws = (char*)d_ws;
  size_t off = 0;
  auto alloc = [&](size_t n) -> char* {
    off = (off + 255) & ~(size_t)255;
    char* p = ws + off; off += n; return p;
  };
  int*    deg       = (int*)   alloc((size_t)N_NODES*4);
  int*    cursor    = (int*)   alloc((size_t)N_NODES*4);
  int*    row_start = (int*)   alloc((size_t)(N_NODES+1)*4);
  float*  dinv      = (float*) alloc((size_t)N_NODES*4);
  int*    lexc      = (int*)   alloc((size_t)N_NODES*4);
  int*    bsum      = (int*)   alloc((size_t)SCAN_NB*4);
  int*    boff      = (int*)   alloc((size_t)SCAN_NB*4);
  int*    csr_src   = (int*)   alloc((size_t)N_EDGES*4);
  ushort* wt_emb    = (ushort*)alloc((size_t)768*HID*2);
  ushort* wt_c1     = (ushort*)alloc((size_t)HID*HID*2);
  ushort* wt_c2     = (ushort*)alloc((size_t)HID*HID*2);
  ushort* t1        = (ushort*)alloc((size_t)N_NODES*HID*2);
  ushort* h2        = (ushort*)alloc((size_t)N_NODES*HID*2);
  uint*   hw        = (uint*)  alloc((size_t)N_NODES*64*4);   // packed bf16 x2, column-chunked
  float*  g         = (float*) alloc((size_t)N_GRAPHS*HID*4);
  int*    gstart    = (int*)   alloc((size_t)(N_GRAPHS+1)*4);

  hipMemsetAsync(deg,    0, (size_t)N_NODES*4, stream);
  hipMemsetAsync(cursor, 0, (size_t)N_NODES*4, stream);
  hipMemsetAsync(g,      0, (size_t)N_GRAPHS*HID*4, stream);

  int eb = (N_EDGES + 255) / 256;
  int nb = (N_NODES + 255) / 256;
  k_count  <<<eb, 256, 0, stream>>>(dst, deg, N_EDGES);
  k_scan1  <<<SCAN_NB, SCAN_BS, 0, stream>>>(deg, lexc, bsum, dinv, N_NODES);
  k_scan2  <<<1, 256, 0, stream>>>(bsum, boff, row_start);
  k_scan3  <<<nb, 256, 0, stream>>>(lexc, boff, row_start, N_NODES);
  k_scatter<<<eb, 256, 0, stream>>>(src, dst, row_start, cursor, csr_src, N_EDGES);
  k_ranges <<<1, 256, 0, stream>>>(batch, gstart, N_NODES, N_GRAPHS);

  k_wt3<<<(768*HID + 2*HID*HID + 255)/256, 256, 0, stream>>>(W_emb, wt_emb, W_c1, wt_c1, W_c2, wt_c2);

  int gemm_blocks = (N_NODES + 63) / 64;
  // t1 = x @ W_emb + b_emb (bf16, row layout)
  k_gemm<768, true,  true,  true,  false, false><<<gemm_blocks, 256, 0, stream>>>(x,  wt_emb, b_emb, nullptr, t1, N_NODES);
  // hw = (t1 @ W_c1) * dinv[row]  (packed bf16, column-chunked)
  k_gemm<128, false, true,  false, true,  true ><<<gemm_blocks, 256, 0, stream>>>(t1, wt_c1, nullptr, dinv, hw, N_NODES);
  // h2 = relu(agg(hw) + b_c1) (bf16, row layout)
  k_agg<true,  false><<<N_NODES, 256, 0, stream>>>(hw, row_start, csr_src, dinv, b_c1,
                                                   (uint*)h2, nullptr, nullptr, nullptr);
  // hw = (h2 @ W_c2) * dinv[row] (packed bf16, column-chunked)
  k_gemm<128, false, true,  false, true,  true ><<<gemm_blocks, 256, 0, stream>>>(h2, wt_c2, nullptr, dinv, hw, N_NODES);
  // g += pooled(agg(hw) + b_c2)   (fused)
  k_agg<false, true ><<<N_NODES, 256, 0, stream>>>(hw, row_start, csr_src, dinv, b_c2,
                                                   nullptr, batch, gstart, g);

  k_head<<<N_GRAPHS, 128, 0, stream>>>(g, W_l1, b_l1, W_l2, b_l2, out);
}

// Round 3
// 610.447 us; speedup vs baseline: 1.0988x; 1.0988x over previous
//
#include <hip/hip_runtime.h>
#include <hip/hip_bf16.h>

#define N_NODES  50000
#define N_GRAPHS 128
#define N_EDGES  800000
#define HID      128
#define SCAN_BS  256
#define SCAN_NB  ((N_NODES + SCAN_BS - 1) / SCAN_BS)

typedef __attribute__((ext_vector_type(8))) short short8;
typedef __attribute__((ext_vector_type(4))) float f32x4;

static __device__ __forceinline__ ushort f2bf(float f){
  __hip_bfloat16 h = __float2bfloat16(f);
  return *reinterpret_cast<ushort*>(&h);
}
static __device__ __forceinline__ float bf_lo(uint pk){ return __uint_as_float(pk << 16); }
static __device__ __forceinline__ float bf_hi(uint pk){ return __uint_as_float(pk & 0xffff0000u); }

// ---------------- graph preprocessing ----------------

__global__ void k_count(const int* __restrict__ dst, int* __restrict__ deg, int E){
  int i = blockIdx.x*blockDim.x + threadIdx.x;
  if (i < E) atomicAdd(&deg[dst[i]], 1);
}

__global__ void k_scan1(const int* __restrict__ deg, int* __restrict__ lexc,
                        int* __restrict__ bsum, float* __restrict__ dinv, int N){
  __shared__ int s[SCAN_BS];
  int t = threadIdx.x, i = blockIdx.x*SCAN_BS + t;
  int v = (i < N) ? deg[i] : 0;
  if (i < N) dinv[i] = rsqrtf((float)(v + 1));   // +1 self loop
  s[t] = v;
  __syncthreads();
  int acc = v;
  for (int d = 1; d < SCAN_BS; d <<= 1){
    int u = (t >= d) ? s[t-d] : 0;
    __syncthreads();
    acc += u; s[t] = acc;
    __syncthreads();
  }
  if (i < N) lexc[i] = acc - v;
  if (t == SCAN_BS-1) bsum[blockIdx.x] = acc;
}

__global__ void k_scan2(const int* __restrict__ bsum, int* __restrict__ boff,
                        int* __restrict__ row_start){
  __shared__ int s[SCAN_NB];
  int t = threadIdx.x;
  int v = (t < SCAN_NB) ? bsum[t] : 0;
  if (t < SCAN_NB) s[t] = v;
  __syncthreads();
  int acc = v;
  for (int d = 1; d < SCAN_NB; d <<= 1){
    int u = (t >= d && t - d < SCAN_NB) ? s[t-d] : 0;
    __syncthreads();
    if (t < SCAN_NB){ acc += u; s[t] = acc; }
    __syncthreads();
  }
  if (t < SCAN_NB) boff[t] = acc - v;
  if (t == SCAN_NB-1) row_start[N_NODES] = acc;
}

__global__ void k_scan3(const int* __restrict__ lexc, const int* __restrict__ boff,
                        int* __restrict__ row_start, int N){
  int i = blockIdx.x*blockDim.x + threadIdx.x;
  if (i < N) row_start[i] = lexc[i] + boff[i >> 8];
}

__global__ void k_scatter(const int* __restrict__ src, const int* __restrict__ dst,
                          const int* __restrict__ row_start, int* __restrict__ cursor,
                          int* __restrict__ csr_src, int E){
  int i = blockIdx.x*blockDim.x + threadIdx.x;
  if (i >= E) return;
  int d = dst[i];
  int pos = row_start[d] + atomicAdd(&cursor[d], 1);
  csr_src[pos] = src[i];
}

// transpose + bf16-convert the three weight matrices in one launch
__global__ void k_wt3(const float* __restrict__ W0, ushort* __restrict__ T0,
                      const float* __restrict__ W1, ushort* __restrict__ T1,
                      const float* __restrict__ W2, ushort* __restrict__ T2){
  int idx = blockIdx.x*blockDim.x + threadIdx.x;
  if (idx < 768*HID){
    int k = idx >> 7, n = idx & 127;
    T0[n*768 + k] = f2bf(W0[idx]);
  } else if (idx < 768*HID + HID*HID){
    int j = idx - 768*HID; int k = j >> 7, n = j & 127;
    T1[n*HID + k] = f2bf(W1[j]);
  } else if (idx < 768*HID + 2*HID*HID){
    int j = idx - 768*HID - HID*HID; int k = j >> 7, n = j & 127;
    T2[n*HID + k] = f2bf(W2[j]);
  }
}

// ---------------- bf16 MFMA GEMM: Out[M][128] = A[M][K] @ W[K][128] ----------------
// CHUNKED (with OUT_BF16): write output column-chunked for the L2-pinned gather:
//   ushort index = (n>>5) * (M*32) + row*32 + (n&31)   (4 chunks of 32 cols = 64 B/row)

template<int K, bool A_F32, bool OUT_BF16, bool BIAS, bool SCALE, bool CHUNKED>
__global__ __launch_bounds__(256) void k_gemm(const void* __restrict__ Aptr,
                                              const ushort* __restrict__ Wt,
                                              const float* __restrict__ bias,
                                              const float* __restrict__ rowscale,
                                              void* __restrict__ Outp, int M){
  __shared__ __align__(16) ushort lA[64*32];    // [row][k]
  __shared__ __align__(16) ushort lB[128*32];   // [n][k]
  int tid  = threadIdx.x;
  int wave = tid >> 6, lane = tid & 63;
  int kg   = lane >> 4, lr = lane & 15;
  int m0   = blockIdx.x * 64;

  f32x4 acc[8];
  #pragma unroll
  for (int i = 0; i < 8; i++) acc[i] = f32x4{0.f, 0.f, 0.f, 0.f};

  for (int k0 = 0; k0 < K; k0 += 32){
    if (A_F32){
      const float* A = (const float*)Aptr;
      #pragma unroll
      for (int i = 0; i < 2; i++){
        int l = tid + i*256;
        int r = l >> 3, c4 = (l & 7) * 4;
        int gm = m0 + r;
        float4 v = make_float4(0.f, 0.f, 0.f, 0.f);
        if (gm < M) v = *(const float4*)(A + (size_t)gm*K + k0 + c4);
        ushort4 u; u.x = f2bf(v.x); u.y = f2bf(v.y); u.z = f2bf(v.z); u.w = f2bf(v.w);
        *(ushort4*)&lA[r*32 + c4] = u;
      }
    } else {
      const ushort* A = (const ushort*)Aptr;
      int r = tid >> 2, c8 = (tid & 3) * 8;
      int gm = m0 + r;
      int4 v = make_int4(0, 0, 0, 0);
      if (gm < M) v = *(const int4*)(A + (size_t)gm*K + k0 + c8);
      *(int4*)&lA[r*32 + c8] = v;
    }
    #pragma unroll
    for (int i = 0; i < 2; i++){
      int l = tid + i*256;
      int n = l >> 2, c8 = (l & 3) * 8;
      *(int4*)&lB[n*32 + c8] = *(const int4*)(Wt + (size_t)n*K + k0 + c8);
    }
    __syncthreads();

    short8 a = *(const short8*)&lA[(wave*16 + lr)*32 + kg*8];
    #pragma unroll
    for (int nt = 0; nt < 8; nt++){
      short8 b = *(const short8*)&lB[(nt*16 + lr)*32 + kg*8];
      acc[nt] = __builtin_amdgcn_mfma_f32_16x16x32_bf16(a, b, acc[nt], 0, 0, 0);
    }
    __syncthreads();
  }

  #pragma unroll
  for (int nt = 0; nt < 8; nt++){
    #pragma unroll
    for (int r = 0; r < 4; r++){
      int gm = m0 + wave*16 + kg*4 + r;
      int n  = nt*16 + lr;
      if (gm < M){
        float v = acc[nt][r];
        if (BIAS)  v += bias[n];
        if (SCALE) v *= rowscale[gm];
        if (OUT_BF16){
          if (CHUNKED)
            ((ushort*)Outp)[(size_t)(n >> 5)*((size_t)M*32) + (size_t)gm*32 + (n & 31)] = f2bf(v);
          else
            ((ushort*)Outp)[(size_t)gm*HID + n] = f2bf(v);
        } else {
          ((float*)Outp)[(size_t)gm*HID + n] = v;
        }
      }
    }
  }
}

// ---------------- edge aggregation (L2-pinned column chunks, amortized) ----------------
// hw column-chunked: hwc[chunk][node][16 uints] (chunk = 32 cols = 64 B/row, 3.2 MB
// fits an XCD's 4 MB L2). chunk = blockIdx&3 -> XCD-pinned (round-1: FETCH 80->24 MB).
// Wave = 4 NODES x 1 chunk (q = lane>>4 selects node, p = lane&15 selects uint).
// Per round, 16 edges per node staged from csr_src (one coalesced 64B segment per
// group); edge t broadcast within each 16-lane group via ds_swizzle BitMode
// ((self&0x10)|t within each 32-lane half == group-base + t); 16 gather loads in
// flight, each covering 4 nodes' 64B chunk-rows. Masked slots gather row 0,
// contribution zeroed via mask-FMA. ds_swizzle imm must be a literal -> macro unroll.

#define AGG_GATHER(t) { \
    int s_##t = __builtin_amdgcn_ds_swizzle(sl, ((t) << 5) | 0x10); \
    v[t] = hc[(uint)s_##t*16u + (uint)p]; }

template<bool RELU, bool FUSE_POOL>
__global__ __launch_bounds__(256, 4) void k_agg(const uint* __restrict__ hwc,
                                                const int* __restrict__ row_start,
                                                const int* __restrict__ csr_src,
                                                const float* __restrict__ dinv,
                                                const float* __restrict__ bias,
                                                uint* __restrict__ OutBf,
                                                const int* __restrict__ batch,
                                                const int* __restrict__ gstart,
                                                float* __restrict__ g){
  int wave = threadIdx.x >> 6, lane = threadIdx.x & 63;
  int chunk = blockIdx.x & 3;
  int grp   = blockIdx.x >> 2;              // 0..3124, 16 nodes per block
  int p = lane & 15, q = lane >> 4;
  int node  = grp*16 + wave*4 + q;
  const uint* __restrict__ hc = hwc + (size_t)chunk * ((size_t)N_NODES*16);

  int b0 = row_start[node], e0 = row_start[node+1];
  int deg = e0 - b0;
  int dmax = max(deg, __shfl_xor(deg, 16));  // max degree over the wave's 4 nodes
  dmax = max(dmax, __shfl_xor(dmax, 32));

  uint pk0 = hc[(size_t)node*16 + p];       // self loop; coalesced 256B per wave
  float ax = bf_lo(pk0), ay = bf_hi(pk0);

  for (int r = 0; r < dmax; r += 16){
    int t16 = r + p;
    int sl = (t16 < deg) ? csr_src[b0 + t16] : 0;   // group q stages its node's edges
    uint v[16];
    AGG_GATHER(0)  AGG_GATHER(1)  AGG_GATHER(2)  AGG_GATHER(3)
    AGG_GATHER(4)  AGG_GATHER(5)  AGG_GATHER(6)  AGG_GATHER(7)
    AGG_GATHER(8)  AGG_GATHER(9)  AGG_GATHER(10) AGG_GATHER(11)
    AGG_GATHER(12) AGG_GATHER(13) AGG_GATHER(14) AGG_GATHER(15)
    #pragma unroll
    for (int t = 0; t < 16; t++){
      float mk = (r + t < deg) ? 1.0f : 0.0f;
      ax += mk * bf_lo(v[t]);
      ay += mk * bf_hi(v[t]);
    }
  }

  float dd = dinv[node];
  float2 bb = ((const float2*)bias)[chunk*16 + p];
  float vx = ax*dd + bb.x;
  float vy = ay*dd + bb.y;
  if (RELU){ vx = fmaxf(vx, 0.f); vy = fmaxf(vy, 0.f); }

  if (FUSE_POOL){
    int bg = batch[node];
    float cnt = (float)(gstart[bg+1] - gstart[bg]);
    float sc = 1.0f / fmaxf(cnt, 1.0f);
    int col = chunk*32 + 2*p;
    atomicAdd(&g[bg*HID + col],     vx*sc);
    atomicAdd(&g[bg*HID + col + 1], vy*sc);
  } else {
    uint pk = (uint)f2bf(vx) | ((uint)f2bf(vy) << 16);
    OutBf[(size_t)node*64 + chunk*16 + p] = pk;   // standard row layout for next GEMM
  }
}

// ---------------- head ----------------

__global__ void k_ranges(const int* __restrict__ batch, int* __restrict__ gstart, int N, int G){
  int b = blockIdx.x*blockDim.x + threadIdx.x;
  if (b > G) return;
  int lo = 0, hi = N;
  while (lo < hi){ int mid = (lo + hi) >> 1; if (batch[mid] < b) lo = mid + 1; else hi = mid; }
  gstart[b] = lo;
}

__global__ void k_head(const float* __restrict__ g, const float* __restrict__ W1,
                       const float* __restrict__ b1, const float* __restrict__ W2,
                       const float* __restrict__ b2, float* __restrict__ out){
  __shared__ float row[128];
  __shared__ float z[128];
  int b = blockIdx.x, t = threadIdx.x;
  row[t] = g[b*HID + t];
  __syncthreads();
  float a = b1[t];
  #pragma unroll 8
  for (int k = 0; k < 128; k++) a += row[k] * W1[k*128 + t];
  z[t] = fmaxf(a, 0.f);
  __syncthreads();
  if (t < 3){
    float o = b2[t];
    #pragma unroll 8
    for (int k = 0; k < 128; k++) o += z[k] * W2[k*3 + t];
    out[b*3 + t] = o;
  }
}

// ---------------- launch ----------------

extern "C" void kernel_launch(void* const* d_in, const int* in_sizes, int n_in,
                              void* d_out, int out_size, void* d_ws, size_t ws_size,
                              hipStream_t stream) {
  const float* x     = (const float*)d_in[0];
  const int*   ei    = (const int*)  d_in[1];
  const int*   batch = (const int*)  d_in[2];
  const float* W_emb = (const float*)d_in[3];
  const float* b_emb = (const float*)d_in[4];
  const float* W_c1  = (const float*)d_in[5];
  const float* b_c1  = (const float*)d_in[6];
  const float* W_c2  = (const float*)d_in[7];
  const float* b_c2  = (const float*)d_in[8];
  const float* W_l1  = (const float*)d_in[9];
  const float* b_l1  = (const float*)d_in[10];
  const float* W_l2  = (const float*)d_in[11];
  const float* b_l2  = (const float*)d_in[12];
  const int* src = ei;
  const int* dst = ei + N_EDGES;
  float* out = (float*)d_out;

  char* ws = (char*)d_ws;
  size_t off = 0;
  auto alloc = [&](size_t n) -> char* {
    off = (off + 255) & ~(size_t)255;
    char* p = ws + off; off += n; return p;
  };
  int*    deg       = (int*)   alloc((size_t)N_NODES*4);
  int*    cursor    = (int*)   alloc((size_t)N_NODES*4);
  int*    row_start = (int*)   alloc((size_t)(N_NODES+1)*4);
  float*  dinv      = (float*) alloc((size_t)N_NODES*4);
  int*    lexc      = (int*)   alloc((size_t)N_NODES*4);
  int*    bsum      = (int*)   alloc((size_t)SCAN_NB*4);
  int*    boff      = (int*)   alloc((size_t)SCAN_NB*4);
  int*    csr_src   = (int*)   alloc((size_t)N_EDGES*4);
  ushort* wt_emb    = (ushort*)alloc((size_t)768*HID*2);
  ushort* wt_c1     = (ushort*)alloc((size_t)HID*HID*2);
  ushort* wt_c2     = (ushort*)alloc((size_t)HID*HID*2);
  ushort* t1        = (ushort*)alloc((size_t)N_NODES*HID*2);
  ushort* h2        = (ushort*)alloc((size_t)N_NODES*HID*2);
  uint*   hw        = (uint*)  alloc((size_t)N_NODES*64*4);   // packed bf16 x2, column-chunked
  float*  g         = (float*) alloc((size_t)N_GRAPHS*HID*4);
  int*    gstart    = (int*)   alloc((size_t)(N_GRAPHS+1)*4);

  hipMemsetAsync(deg,    0, (size_t)N_NODES*4, stream);
  hipMemsetAsync(cursor, 0, (size_t)N_NODES*4, stream);
  hipMemsetAsync(g,      0, (size_t)N_GRAPHS*HID*4, stream);

  int eb = (N_EDGES + 255) / 256;
  int nb = (N_NODES + 255) / 256;
  k_count  <<<eb, 256, 0, stream>>>(dst, deg, N_EDGES);
  k_scan1  <<<SCAN_NB, SCAN_BS, 0, stream>>>(deg, lexc, bsum, dinv, N_NODES);
  k_scan2  <<<1, 256, 0, stream>>>(bsum, boff, row_start);
  k_scan3  <<<nb, 256, 0, stream>>>(lexc, boff, row_start, N_NODES);
  k_scatter<<<eb, 256, 0, stream>>>(src, dst, row_start, cursor, csr_src, N_EDGES);
  k_ranges <<<1, 256, 0, stream>>>(batch, gstart, N_NODES, N_GRAPHS);

  k_wt3<<<(768*HID + 2*HID*HID + 255)/256, 256, 0, stream>>>(W_emb, wt_emb, W_c1, wt_c1, W_c2, wt_c2);

  int gemm_blocks = (N_NODES + 63) / 64;
  int agg_blocks  = (N_NODES / 16) * 4;     // 3125 node-groups x 4 chunks = 12500
  // t1 = x @ W_emb + b_emb (bf16, row layout)
  k_gemm<768, true,  true,  true,  false, false><<<gemm_blocks, 256, 0, stream>>>(x,  wt_emb, b_emb, nullptr, t1, N_NODES);
  // hw = (t1 @ W_c1) * dinv[row]  (packed bf16, column-chunked)
  k_gemm<128, false, true,  false, true,  true ><<<gemm_blocks, 256, 0, stream>>>(t1, wt_c1, nullptr, dinv, hw, N_NODES);
  // h2 = relu(agg(hw) + b_c1) (bf16, row layout)
  k_agg<true,  false><<<agg_blocks, 256, 0, stream>>>(hw, row_start, csr_src, dinv, b_c1,
                                                      (uint*)h2, nullptr, nullptr, nullptr);
  // hw = (h2 @ W_c2) * dinv[row] (packed bf16, column-chunked)
  k_gemm<128, false, true,  false, true,  true ><<<gemm_blocks, 256, 0, stream>>>(h2, wt_c2, nullptr, dinv, hw, N_NODES);
  // g += pooled(agg(hw) + b_c2)   (fused)
  k_agg<false, true ><<<agg_blocks, 256, 0, stream>>>(hw, row_start, csr_src, dinv, b_c2,
                                                      nullptr, batch, gstart, g);

  k_head<<<N_GRAPHS, 128, 0, stream>>>(g, W_l1, b_l1, W_l2, b_l2, out);
}